// Round 4
// baseline (86.196 us; speedup 1.0000x reference)
//
#include <hip/hip_runtime.h>
#include <math.h>

#define HIDDEN 128
#define NGRAPH 16384
#define GPB 16                  // graphs per block
#define NBLK (NGRAPH / GPB)     // 1024 blocks -> 4 blocks/CU resident

// shifted-softplus shift = log(2)
__device__ __constant__ float kSHIFT = 0.69314718055994530942f;

// ---------------------------------------------------------------------------
// Kernel 0: boundary scan. batch sorted; thread i writes offs[g]=i for every
// graph g starting at i (covers empty graphs). offs[NGRAPH]=n_nodes.
// ---------------------------------------------------------------------------
__global__ __launch_bounds__(256) void offsets_kernel(
    const int* __restrict__ batch, int* __restrict__ offs, int n_nodes)
{
    int i = blockIdx.x * blockDim.x + threadIdx.x;
    if (i >= n_nodes) return;
    int b = batch[i];
    int prev = (i == 0) ? -1 : batch[i - 1];
    for (int g = prev + 1; g <= b; ++g) offs[g] = i;        // rare
    if (i == n_nodes - 1)
        for (int g = b + 1; g <= NGRAPH; ++g) offs[g] = n_nodes;
}

// ---------------------------------------------------------------------------
// Fused kernel: 1024 blocks x 256 threads, 16 graphs per block.
// Phase 1: each of 4 waves streams 4 graphs' contiguous node ranges
//   (float4 coalesced, 4 accumulators = 4 loads in flight/lane; offsets
//   prefetched once per wave), shfl-reduce across wave halves, u rows go
//   straight to LDS (u never touches HBM).
// Phase 2: 16-row x 256-col MLP tile, acc[2][8] register blocking, W1
//   staged in 16-k-row chunks (16 KB). Epilogue: bias -> shifted softplus
//   -> W2 dot -> 32-lane shuffle reduce.
// LDS: 8 KB u_s + 16 KB w_s = 24 KB; launch_bounds(256,4) -> 4 blocks/CU
//   (16 waves/CU) for latency hiding + cross-block phase overlap.
// ---------------------------------------------------------------------------
__global__ __launch_bounds__(256, 4) void fused_kernel(
    const float* __restrict__ v, const int* __restrict__ offs,
    const float* __restrict__ W1, const float* __restrict__ b1,
    const float* __restrict__ W2, const float* __restrict__ b2,
    float* __restrict__ out)
{
    __shared__ float u_s[GPB * HIDDEN];   // 8 KB
    __shared__ float w_s[16 * 256];       // 16 KB

    const int t  = threadIdx.x;
    const int l  = t & 63;
    const int w  = t >> 6;                 // wave id 0..3
    const int g0 = blockIdx.x * GPB;

    const int f4 = l & 31;                 // float4 column 0..31
    const int ro = l >> 5;                 // row half 0..1

    const float4* __restrict__ v4 = reinterpret_cast<const float4*>(v);
    float4* u_s4 = reinterpret_cast<float4*>(u_s);

    // ---------------- Phase 1: segment sums into LDS ----------------
    // prefetch this wave's 5 offsets (graphs w*4 .. w*4+3)
    int o[5];
    #pragma unroll
    for (int q = 0; q < 5; ++q) o[q] = offs[g0 + w * 4 + q];

    for (int gi = 0; gi < 4; ++gi) {
        const int gl    = w * 4 + gi;              // local graph 0..15
        const int start = o[gi];
        const int end   = o[gi + 1];

        float4 a0 = make_float4(0.f, 0.f, 0.f, 0.f);
        float4 a1 = a0, a2 = a0, a3 = a0;
        int r = start + ro;
        for (; r + 6 < end; r += 8) {
            float4 x0 = v4[(size_t)r       * 32 + f4];
            float4 x1 = v4[(size_t)(r + 2) * 32 + f4];
            float4 x2 = v4[(size_t)(r + 4) * 32 + f4];
            float4 x3 = v4[(size_t)(r + 6) * 32 + f4];
            a0.x += x0.x; a0.y += x0.y; a0.z += x0.z; a0.w += x0.w;
            a1.x += x1.x; a1.y += x1.y; a1.z += x1.z; a1.w += x1.w;
            a2.x += x2.x; a2.y += x2.y; a2.z += x2.z; a2.w += x2.w;
            a3.x += x3.x; a3.y += x3.y; a3.z += x3.z; a3.w += x3.w;
        }
        for (; r < end; r += 2) {
            float4 x = v4[(size_t)r * 32 + f4];
            a0.x += x.x; a0.y += x.y; a0.z += x.z; a0.w += x.w;
        }
        float4 s;
        s.x = (a0.x + a1.x) + (a2.x + a3.x);
        s.y = (a0.y + a1.y) + (a2.y + a3.y);
        s.z = (a0.z + a1.z) + (a2.z + a3.z);
        s.w = (a0.w + a1.w) + (a2.w + a3.w);
        s.x += __shfl_xor(s.x, 32);
        s.y += __shfl_xor(s.y, 32);
        s.z += __shfl_xor(s.z, 32);
        s.w += __shfl_xor(s.w, 32);
        if (ro == 0) u_s4[gl * 32 + f4] = s;
    }
    __syncthreads();

    // ---------------- Phase 2: MLP on the 16-row tile ----------------
    const int cg = t & 31;   // col group: cols cg + 32j
    const int rg = t >> 5;   // row group: rows rg + 8i (i in 0..1)

    float acc[2][8];
    #pragma unroll
    for (int i = 0; i < 2; ++i)
        #pragma unroll
        for (int j = 0; j < 8; ++j) acc[i][j] = 0.f;

    const float4* __restrict__ W14 = reinterpret_cast<const float4*>(W1);
    float4* w_s4 = reinterpret_cast<float4*>(w_s);

    for (int kc = 0; kc < 8; ++kc) {          // 8 chunks of 16 k-rows
        if (kc) __syncthreads();
        #pragma unroll
        for (int q = 0; q < 4; ++q)
            w_s4[t + 256 * q] = W14[kc * 1024 + t + 256 * q];
        __syncthreads();

        #pragma unroll
        for (int k4 = 0; k4 < 16; k4 += 4) {
            float4 a4[2];
            #pragma unroll
            for (int i = 0; i < 2; ++i)
                a4[i] = *reinterpret_cast<const float4*>(
                    &u_s[(rg + 8 * i) * 128 + kc * 16 + k4]);
            #pragma unroll
            for (int kk = 0; kk < 4; ++kk) {
                float b[8];
                #pragma unroll
                for (int j = 0; j < 8; ++j)
                    b[j] = w_s[(k4 + kk) * 256 + cg + 32 * j];
                #pragma unroll
                for (int i = 0; i < 2; ++i) {
                    float av = (kk == 0) ? a4[i].x : (kk == 1) ? a4[i].y
                             : (kk == 2) ? a4[i].z : a4[i].w;
                    #pragma unroll
                    for (int j = 0; j < 8; ++j)
                        acc[i][j] = fmaf(av, b[j], acc[i][j]);
                }
            }
        }
    }

    // epilogue: bias, shifted softplus, W2 contraction, 32-lane reduce
    const float bias2 = b2[0];
    #pragma unroll
    for (int i = 0; i < 2; ++i) {
        float partial = 0.f;
        #pragma unroll
        for (int j = 0; j < 8; ++j) {
            int c = cg + 32 * j;
            float x = acc[i][j] + b1[c];
            float h = fmaxf(x, 0.f) + log1pf(expf(-fabsf(x))) - kSHIFT;
            partial += h * W2[c];
        }
        #pragma unroll
        for (int m = 16; m >= 1; m >>= 1)
            partial += __shfl_xor(partial, m);
        if (cg == 0)
            out[g0 + rg + 8 * i] = partial + bias2;
    }
}

extern "C" void kernel_launch(void* const* d_in, const int* in_sizes, int n_in,
                              void* d_out, int out_size, void* d_ws, size_t ws_size,
                              hipStream_t stream) {
    const float* v     = (const float*)d_in[0];
    const int*   batch = (const int*)d_in[1];
    const float* W1    = (const float*)d_in[2];
    const float* b1    = (const float*)d_in[3];
    const float* W2    = (const float*)d_in[4];
    const float* b2    = (const float*)d_in[5];
    float* out = (float*)d_out;

    const int n_nodes = in_sizes[0] / HIDDEN;   // 500000
    int* offs = (int*)d_ws;                     // (NGRAPH+1) ints

    offsets_kernel<<<(n_nodes + 255) / 256, 256, 0, stream>>>(batch, offs, n_nodes);
    fused_kernel<<<NBLK, 256, 0, stream>>>(v, offs, W1, b1, W2, b2, out);
}